// Round 10
// baseline (753.844 us; speedup 1.0000x reference)
//
#include <hip/hip_runtime.h>
#include <hip/hip_bf16.h>

// n=4, c=512, h=w=64. Runtime dtype via detect_f32 (R3-proven).
#define NBATCH 4
#define C 512
#define HW 4096
#define GROUPS 32
#define EPSV 1e-5f
// attention scale folded with 1/ln2 (softmax in exp2 domain, R5-proven):
// 1/sqrt(512) * log2(e)
#define ATTN_SCALE_L2 0.0637587085f

typedef short bf16x8 __attribute__((ext_vector_type(8)));  // 8 bf16 = 4 VGPR
typedef float f32x4 __attribute__((ext_vector_type(4)));

__device__ __forceinline__ float bf(unsigned short u) {
  return __uint_as_float(((unsigned)u) << 16);
}
__device__ __forceinline__ unsigned short fb(float v) {
  __hip_bfloat16 h = __float2bfloat16(v);
  return *(unsigned short*)&h;
}
__device__ __forceinline__ bf16x8 frag_ld(const short* p) {
  return *(const bf16x8*)p;  // 16B-aligned by construction
}
#define MFMA(a, b, c) __builtin_amdgcn_mfma_f32_16x16x32_bf16((a), (b), (c), 0, 0, 0)

#define SCHED_FENCE() __builtin_amdgcn_sched_barrier(0)
// raw barrier (NO vmcnt drain) + compiler/scheduler fences (rule #18 / m152)
#define BAR()                                   \
  do {                                          \
    asm volatile("" ::: "memory");              \
    SCHED_FENCE();                              \
    __builtin_amdgcn_s_barrier();               \
    SCHED_FENCE();                              \
    asm volatile("" ::: "memory");              \
  } while (0)
#define WAITV(N)                                                  \
  do {                                                            \
    asm volatile("s_waitcnt vmcnt(" #N ")" ::: "memory");         \
    SCHED_FENCE();                                                \
  } while (0)
// drain DS queue before a raw barrier that PUBLISHES cross-wave LDS writes
// (raw s_barrier does not imply waitcnt; __syncthreads does).
#define WAITLGKM()                                                \
  do {                                                            \
    asm volatile("s_waitcnt lgkmcnt(0)" ::: "memory");            \
    SCHED_FENCE();                                                \
  } while (0)

// async global->LDS, 16B per lane; LDS dest is wave-uniform base + lane*16
__device__ __forceinline__ void gl_lds16(const short* g, short* l) {
  __builtin_amdgcn_global_load_lds(
      (const __attribute__((address_space(1))) unsigned int*)g,
      (__attribute__((address_space(3))) unsigned int*)l, 16, 0, 0);
}

__device__ __forceinline__ void unpack8(uint4 w, float* f) {
  f[0] = __uint_as_float(w.x << 16);
  f[1] = __uint_as_float(w.x & 0xFFFF0000u);
  f[2] = __uint_as_float(w.y << 16);
  f[3] = __uint_as_float(w.y & 0xFFFF0000u);
  f[4] = __uint_as_float(w.z << 16);
  f[5] = __uint_as_float(w.z & 0xFFFF0000u);
  f[6] = __uint_as_float(w.w << 16);
  f[7] = __uint_as_float(w.w & 0xFFFF0000u);
}

// Runtime dtype detection (R3-proven).
__device__ __forceinline__ bool detect_f32(const void* w_in) {
  const unsigned short* u = (const unsigned short*)w_in;
  bool f32 = false;
#pragma unroll
  for (int i = 0; i < 64; ++i) {
    float v = bf(u[i]);
    if (!(fabsf(v) < 1e3f)) f32 = true;  // NaN -> true
  }
  return f32;
}
__device__ __forceinline__ float ld(const void* p, size_t i, bool f32) {
  if (f32) return ((const float*)p)[i];
  return bf(((const unsigned short*)p)[i]);
}

// Stage GN-normalized x rows [t0, t0+32) into xn[32][520] (bf16). R3-proven.
__device__ __forceinline__ void stage_xn(short* xn, const void* x,
                                         const void* gsc, const void* gbi,
                                         const float* stats, int nn, int t0,
                                         bool f32) {
  const int tid = threadIdx.x;
  const int part = tid & 3, crel = tid >> 2;
  for (int c0 = 0; c0 < 512; c0 += 64) {
    int c = c0 + crel;
    float rr = stats[128 + nn * GROUPS + (c >> 4)];
    float mu = stats[nn * GROUPS + (c >> 4)];
    float scl = ld(gsc, c, f32) * rr;
    float sft = ld(gbi, c, f32) - mu * scl;
    float f[8];
    if (f32) {
      const float4* p = (const float4*)((const float*)x +
                                        ((size_t)(nn * C + c) << 12) + t0 + part * 8);
      float4 r0 = p[0], r1 = p[1];
      f[0] = r0.x; f[1] = r0.y; f[2] = r0.z; f[3] = r0.w;
      f[4] = r1.x; f[5] = r1.y; f[6] = r1.z; f[7] = r1.w;
    } else {
      uint4 raw = *(const uint4*)((const unsigned short*)x +
                                  ((size_t)(nn * C + c) << 12) + t0 + part * 8);
      unpack8(raw, f);
    }
#pragma unroll
    for (int j = 0; j < 8; ++j)
      xn[(part * 8 + j) * 520 + c] = (short)fb(f[j] * scl + sft);
  }
}

// ---------------------------------------------------------------------------
// GroupNorm stats — R3-proven verbatim.
// ---------------------------------------------------------------------------
__global__ __launch_bounds__(256) void gn_stats_kernel(
    const void* __restrict__ x, const void* __restrict__ w_in,
    float* __restrict__ stats) {
  const bool f32 = detect_f32(w_in);
  const int b = blockIdx.x;
  const size_t base = (size_t)b << 16;
  float s = 0.f, ss = 0.f;
  for (int i = threadIdx.x; i < 65536; i += 256) {
    float v = ld(x, base + i, f32);
    s += v;
    ss += v * v;
  }
  __shared__ float rs[256], rq[256];
  rs[threadIdx.x] = s;
  rq[threadIdx.x] = ss;
  __syncthreads();
  for (int off = 128; off > 0; off >>= 1) {
    if (threadIdx.x < off) {
      rs[threadIdx.x] += rs[threadIdx.x + off];
      rq[threadIdx.x] += rq[threadIdx.x + off];
    }
    __syncthreads();
  }
  if (threadIdx.x == 0) {
    float m = rs[0] * (1.0f / 65536.0f);
    float var = rq[0] * (1.0f / 65536.0f) - m * m;
    stats[b] = m;
    stats[128 + b] = rsqrtf(var + EPSV);
  }
}

// ---------------------------------------------------------------------------
// wconv — one-time weight conversion to bf16 (R8-proven verbatim).
// ---------------------------------------------------------------------------
__global__ __launch_bounds__(256) void wconv_kernel(
    const void* __restrict__ w_in, const void* __restrict__ w_out,
    short* __restrict__ wbf) {
  const bool f32 = detect_f32(w_in);
  size_t i = ((size_t)blockIdx.x * 256 + threadIdx.x) * 4;
  const void* src;
  size_t off;
  if (i < 786432) {
    src = w_in;
    off = i;
  } else {
    src = w_out;
    off = i - 786432;
  }
  if (f32) {
    float4 v = *(const float4*)((const float*)src + off);
    uint2 u;
    u.x = (unsigned)fb(v.x) | ((unsigned)fb(v.y) << 16);
    u.y = (unsigned)fb(v.z) | ((unsigned)fb(v.w) << 16);
    *(uint2*)(wbf + i) = u;
  } else {
    *(uint2*)(wbf + i) = *(const uint2*)((const unsigned short*)src + off);
  }
}

// ---------------------------------------------------------------------------
// kv_gemm R10 — WEIGHT-REUSE tiling (the R8==R9 invariant says kv_gemm is
// bound by 512MB of LLC weight re-reads, not occupancy/coalescing):
// grid (32, nn, 2): block = 128 t-rows x one half (z=0: K rows 512..1024,
// z=1: V rows 1024..1536). 4 sequential 32-t sub-tiles re-read the block's
// 0.5MB weight set from HOT L2; LLC first-reads drop 512MB -> 128MB.
// Per-output kc order, image layouts, copy-out: byte-identical to R9
// (wave/es ownership refactored 2x16 -> 4x8, same (row,frag) sets).
// ---------------------------------------------------------------------------
__global__ __launch_bounds__(256, 2) void kv_gemm_kernel(
    const void* __restrict__ x, const void* __restrict__ gsc,
    const void* __restrict__ gbi, const float* __restrict__ stats,
    const void* __restrict__ w_in, const void* __restrict__ b_in,
    const short* __restrict__ wbf, unsigned short* __restrict__ kvbase,
    int nn0) {
  const bool f32 = detect_f32(w_in);
  const int nn = nn0 + blockIdx.y;
  unsigned short* kbuf = kvbase + (size_t)blockIdx.y * 4194304;
  unsigned short* vbuf = kbuf + 2097152;
  const int half = blockIdx.z;  // 0 = K, 1 = V
  __shared__ __align__(16) short xn[32 * 520];  // stage + image reuse
  const int tid = threadIdx.x;
  const int wave = tid >> 6, lane = tid & 63, l15 = lane & 15, quad = lane >> 4;
  const int wbase = 512 + half * 512 + wave * 128;  // wave owns 128 w-rows
  (void)lane;

  for (int tsub = 0; tsub < 4; ++tsub) {
    const int t0 = blockIdx.x * 128 + tsub * 32;
    stage_xn(xn, x, gsc, gbi, stats, nn, t0, f32);
    __syncthreads();

    f32x4 acc[8][2];
#pragma unroll
    for (int i = 0; i < 8; ++i) {
      acc[i][0] = {0.f, 0.f, 0.f, 0.f};
      acc[i][1] = {0.f, 0.f, 0.f, 0.f};
    }
    for (int kc = 0; kc < 16; ++kc) {
      bf16x8 b0f = frag_ld(xn + l15 * 520 + kc * 32 + quad * 8);
      bf16x8 b1f = frag_ld(xn + (16 + l15) * 520 + kc * 32 + quad * 8);
#pragma unroll
      for (int es = 0; es < 8; ++es) {
        bf16x8 a = frag_ld(wbf + (size_t)(wbase + es * 16 + l15) * 512 + kc * 32 + quad * 8);
        acc[es][0] = MFMA(a, b0f, acc[es][0]);
        acc[es][1] = MFMA(a, b1f, acc[es][1]);
      }
    }
    __syncthreads();  // xn b-frag reads done; reuse xn[0:16384) as image

    if (half == 0) {
      // K image: [trel][512 e] with granule swizzle g=e>>3 at g^(trel&7)
#pragma unroll
      for (int es = 0; es < 8; ++es) {
        int bidx = wbase + es * 16 + quad * 4;
        float b0 = ld(b_in, bidx, f32), b1 = ld(b_in, bidx + 1, f32);
        float b2 = ld(b_in, bidx + 2, f32), b3 = ld(b_in, bidx + 3, f32);
        int ecol = wave * 128 + es * 16 + quad * 4;
#pragma unroll
        for (int ts = 0; ts < 2; ++ts) {
          int trel = ts * 16 + l15;
          int sw = (((ecol >> 3) ^ (trel & 7)) << 3) | (ecol & 7);
          uint2 u;
          u.x = (unsigned)fb(acc[es][ts][0] + b0) |
                ((unsigned)fb(acc[es][ts][1] + b1) << 16);
          u.y = (unsigned)fb(acc[es][ts][2] + b2) |
                ((unsigned)fb(acc[es][ts][3] + b3) << 16);
          *(uint2*)(xn + trel * 512 + sw) = u;
        }
      }
    } else {
      // V image: [e][32 trel] with granule swizzle (trel>>3)^((e>>1)&3)
#pragma unroll
      for (int es = 0; es < 8; ++es) {
        int bidx = wbase + es * 16 + quad * 4;
        float bb[4] = {ld(b_in, bidx, f32), ld(b_in, bidx + 1, f32),
                       ld(b_in, bidx + 2, f32), ld(b_in, bidx + 3, f32)};
        int ecol = wave * 128 + es * 16 + quad * 4;
#pragma unroll
        for (int ts = 0; ts < 2; ++ts) {
          int trel = ts * 16 + l15;
#pragma unroll
          for (int i = 0; i < 4; ++i) {
            int e = ecol + i;
            xn[e * 32 + ((((trel >> 3) ^ ((e >> 1) & 3)) << 3)) + (trel & 7)] =
                fb(acc[es][ts][i] + bb[i]);
          }
        }
      }
    }
    __syncthreads();
    {  // linear coalesced copy-out: 32KB, 16B/lane
      short* dst = (half == 0) ? (short*)kbuf + (size_t)t0 * 512
                               : (short*)vbuf + (size_t)(t0 >> 5) * 16384;
#pragma unroll
      for (int j = 0; j < 8; ++j) {
        int idx = (j * 256 + tid) * 8;
        *(uint4*)(dst + idx) = *(const uint4*)(xn + idx);
      }
    }
    __syncthreads();  // before next tsub overwrites xn
  }
}

// ---------------------------------------------------------------------------
// flash32 — R8-proven VERBATIM (348-353 µs, two passing rounds): quadrant
// split, parallel hmf publish, split S chains, pre-converted weights.
// ---------------------------------------------------------------------------
__global__ __launch_bounds__(256, 2) void flash32_kernel(
    const void* __restrict__ x, const void* __restrict__ gsc,
    const void* __restrict__ gbi, const float* __restrict__ stats,
    const void* __restrict__ w_in, const void* __restrict__ b_in,
    const short* __restrict__ wbf, const short* __restrict__ wbfo,
    const unsigned short* __restrict__ kvbase,
    const void* __restrict__ b_out, void* __restrict__ out, int nn0,
    int conc) {
  const bool f32 = detect_f32(w_in);
  int nn, t0, slot;
  if (conc) {
    int xcd = blockIdx.x & 7;
    nn = xcd >> 1;
    slot = nn;
    t0 = ((((xcd & 1) << 6) | (blockIdx.x >> 3))) << 5;
  } else {
    nn = nn0; slot = 0; t0 = blockIdx.x << 5;
  }
  const unsigned short* kbuf = kvbase + (size_t)slot * 4194304;
  const unsigned short* vbuf = kbuf + 2097152;

  // LDS: RA 16640 | RB 16640 | Ps 1280 | hmf 256f | lbf 64f = 70,400 B
  __shared__ __align__(16) short lds[35200];
  short* RA = lds;                 // xn (Q phase) -> Ktile -> O park
  short* RB = lds + 16640;         // Qs (Q phase) -> Vtile
  short* Ps = lds + 33280;         // block-shared P [32 qrow][40 t']
  float* hmf = (float*)(lds + 34560);  // [2 th][32 qrow][4 quad] partial max
  float* lbf = (float*)(lds + 35072);  // [2 th][32 qrow] final l halves
  const int tid = threadIdx.x;
  const int wave = tid >> 6, lane = tid & 63, l15 = lane & 15, quad = lane >> 4;
  const int th = wave & 1;   // t' half: rows th*16..+16 of K tile
  const int qh = wave >> 1;  // q half: S quadrant rows qh*16..+16

  // ================= Q phase (R5-proven; weights from wbf) ================
  bf16x8 q[16];  // wave's 16 q-rows x 512 c, B-frag layout (n=qrow, k=c)
  stage_xn(RA, x, gsc, gbi, stats, nn, t0, f32);
  __syncthreads();
  {
    f32x4 qacc[8][2];
#pragma unroll
    for (int i = 0; i < 8; ++i) {
      qacc[i][0] = {0.f, 0.f, 0.f, 0.f};
      qacc[i][1] = {0.f, 0.f, 0.f, 0.f};
    }
    for (int kc = 0; kc < 16; ++kc) {
      bf16x8 bx0 = frag_ld(RA + l15 * 520 + kc * 32 + quad * 8);
      bf16x8 bx1 = frag_ld(RA + (16 + l15) * 520 + kc * 32 + quad * 8);
#pragma unroll
      for (int es = 0; es < 8; ++es) {
        bf16x8 a = frag_ld(wbf + (size_t)(wave * 128 + es * 16 + l15) * 512 + kc * 32 + quad * 8);
        qacc[es][0] = MFMA(a, bx0, qacc[es][0]);
        qacc[es][1] = MFMA(a, bx1, qacc[es][1]);
      }
    }
    // D[m=e][n=t] -> Qs[t][e] = (acc + b_in[e]) * ATTN_SCALE_L2 (bf16)
#pragma unroll
    for (int es = 0; es < 8; ++es) {
      int e0 = wave * 128 + es * 16 + quad * 4;
      float b0 = ld(b_in, e0, f32), b1 = ld(b_in, e0 + 1, f32);
      float b2 = ld(b_in, e0 + 2, f32), b3 = ld(b_in, e0 + 3, f32);
#pragma unroll
      for (int ts = 0; ts < 2; ++ts) {
        int t = ts * 16 + l15;
        uint2 u;
        u.x = (unsigned)fb((qacc[es][ts][0] + b0) * ATTN_SCALE_L2) |
              ((unsigned)fb((qacc[es][ts][1] + b1) * ATTN_SCALE_L2) << 16);
        u.y = (unsigned)fb((qacc[es][ts][2] + b2) * ATTN_SCALE_L2) |
              ((unsigned)fb((qacc[es][ts][3] + b3) * ATTN_SCALE_L2) << 16);
        *(uint2*)(RB + t * 520 + e0) = u;
      }
    }
    __syncthreads();
#pragma unroll
    for (int kc = 0; kc < 16; ++kc)
      q[kc] = frag_ld(RB + (qh * 16 + l15) * 520 + kc * 32 + quad * 8);
    __syncthreads();
  }

// ================= K/V tile staging macros (R5-proven) =================
#define STAGE_K(tk)                                                           \
  {                                                                           \
    const short* s_ = (const short*)kbuf + (size_t)(tk)*16384 + wave * 4096 + \
                      lane * 8;                                               \
    short* d_ = RA + wave * 4096;                                             \
    _Pragma("unroll") for (int i_ = 0; i_ < 8; ++i_)                          \
        gl_lds16(s_ + i_ * 512, d_ + i_ * 512);                               \
  }
#define STAGE_V(tk)                                                           \
  {                                                                           \
    const short* s_ = (const short*)vbuf + (size_t)(tk)*16384 + wave * 4096 + \
                      lane * 8;                                               \
    short* d_ = RB + wave * 4096;                                             \
    _Pragma("unroll") for (int i_ = 0; i_ < 8; ++i_)                          \
        gl_lds16(s_ + i_ * 512, d_ + i_ * 512);                               \
  }

  f32x4 o[2][8];  // O[qh half][e-tile et]: e = wave*128 + et*16 + quad*4+r
#pragma unroll
  for (int hh = 0; hh < 2; ++hh)
#pragma unroll
    for (int et = 0; et < 8; ++et) o[hh][et] = {0.f, 0.f, 0.f, 0.f};
  float mrow2[2] = {-3.0e38f, -3.0e38f};  // running max per q-half (lane=qrow)
  float lpart = 0.f;                      // own-quadrant partial sum

  STAGE_K(0);
  STAGE_V(0);

  for (int tk = 0; tk < 128; ++tk) {
    WAITV(8);  // K(tk) landed (V(tk) may still fly)
    BAR();

    // ---- S quadrant = K[th half] @ Q[qh half]^T: 2 independent chains ----
    f32x4 sA = {0.f, 0.f, 0.f, 0.f}, sB = {0.f, 0.f, 0.f, 0.f};
    __builtin_amdgcn_s_setprio(1);
#pragma unroll
    for (int kc = 0; kc < 16; kc += 2) {
      int g0 = ((kc * 4 + quad) ^ (l15 & 7)) * 8;        // inverse kbuf swz
      int g1 = (((kc + 1) * 4 + quad) ^ (l15 & 7)) * 8;
      bf16x8 kb0 = frag_ld(RA + (th * 16 + l15) * 512 + g0);
      bf16x8 kb1 = frag_ld(RA + (th * 16 + l15) * 512 + g1);
      sA = MFMA(kb0, q[kc], sA);
      sB = MFMA(kb1, q[kc + 1], sB);
    }
    __builtin_amdgcn_s_setprio(0);
    f32x4 s = sA + sB;
    // publish per-quad partial max IMMEDIATELY (no shfl chain)
    float hm = fmaxf(fmaxf(s[0], s[1]), fmaxf(s[2], s[3]));
    hmf[th * 128 + (qh * 16 + l15) * 4 + quad] = hm;
    WAITLGKM();  // publish hmf before raw barrier
    BAR();       // K reads done (stage next) + hmf visible
    if (tk < 127) STAGE_K(tk + 1);  // flies under softmax + PV

    // ---- combined tile max from 4 PARALLEL b128 reads + fmax tree ----
    float4 a0 = *(const float4*)&hmf[l15 * 4];                 // th0, qh0 rows
    float4 a1 = *(const float4*)&hmf[128 + l15 * 4];           // th1, qh0 rows
    float4 c0 = *(const float4*)&hmf[(16 + l15) * 4];          // th0, qh1 rows
    float4 c1 = *(const float4*)&hmf[128 + (16 + l15) * 4];    // th1, qh1 rows
    float m0 = fmaxf(fmaxf(fmaxf(a0.x, a0.y), fmaxf(a0.z, a0.w)),
                     fmaxf(fmaxf(a1.x, a1.y), fmaxf(a1.z, a1.w)));
    float m1 = fmaxf(fmaxf(fmaxf(c0.x, c0.y), fmaxf(c0.z, c0.w)),
                     fmaxf(fmaxf(c1.x, c1.y), fmaxf(c1.z, c1.w)));
    bool grow = (m0 > mrow2[0]) | (m1 > mrow2[1]);
    if (__any(grow)) {  // identical verdict in all waves (shared inputs)
      float n0 = fmaxf(mrow2[0], m0), n1 = fmaxf(mrow2[1], m1);
      float sc0 = exp2f(mrow2[0] - n0), sc1 = exp2f(mrow2[1] - n1);
      mrow2[0] = n0;
      mrow2[1] = n1;
      lpart *= (qh ? sc1 : sc0);
#pragma unroll
      for (int et = 0; et < 8; ++et) {
        o[0][et] *= sc0;
        o[1][et] *= sc1;
      }
    }
    float mq = qh ? mrow2[1] : mrow2[0];
    float p0 = exp2f(s[0] - mq), p1 = exp2f(s[1] - mq);
    float p2 = exp2f(s[2] - mq), p3 = exp2f(s[3] - mq);
    lpart += (p0 + p1) + (p2 + p3);
    uint2 u;
    u.x = (unsigned)fb(p0) | ((unsigned)fb(p1) << 16);
    u.y = (unsigned)fb(p2) | ((unsigned)fb(p3) << 16);
    *(uint2*)(Ps + (qh * 16 + l15) * 40 + th * 16 + quad * 4) = u;
    WAITLGKM();  // publish Ps before raw barrier
    if (tk == 127) { WAITV(0); } else { WAITV(8); }  // V(tk) landed
    BAR();

    // ---- PV: O[e quarter][all 32 q] += V^T @ P; V-frag reused 2x ----
    bf16x8 pa0 = frag_ld(Ps + l15 * 40 + quad * 8);         // qh=0 rows
    bf16x8 pa1 = frag_ld(Ps + (16 + l15) * 40 + quad * 8);  // qh=1 rows
    __builtin_amdgcn_s_setprio(1);
#pragma unroll
    for (int et = 0; et < 8; ++et) {
      int e = wave * 128 + et * 16 + l15;
      bf16x8 vb = frag_ld(RB + e * 32 + ((quad ^ ((l15 >> 1) & 3)) << 3));
      o[0][et] = MFMA(vb, pa0, o[0][et]);
      o[1][et] = MFMA(vb, pa1, o[1][et]);
    }
    __builtin_amdgcn_s_setprio(0);
    BAR();  // V + Ps reads done
    if (tk < 127) STAGE_V(tk + 1);  // flies under next S
  }

  // ---- final l: in-wave quad reduce, cross-wave th combine ----
  lpart += __shfl_xor(lpart, 16);
  lpart += __shfl_xor(lpart, 32);
  if (quad == 0) lbf[th * 32 + qh * 16 + l15] = lpart;
  __syncthreads();
  float inv0 = 1.0f / (lbf[l15] + lbf[32 + l15]);
  float inv1 = 1.0f / (lbf[16 + l15] + lbf[48 + l15]);

  // ---- park O (bf16) in Opark[32][520] over lds base ----
#pragma unroll
  for (int et = 0; et < 8; ++et) {
    uint2 u0, u1;
    u0.x = (unsigned)fb(o[0][et][0] * inv0) | ((unsigned)fb(o[0][et][1] * inv0) << 16);
    u0.y = (unsigned)fb(o[0][et][2] * inv0) | ((unsigned)fb(o[0][et][3] * inv0) << 16);
    u1.x = (unsigned)fb(o[1][et][0] * inv1) | ((unsigned)fb(o[1][et][1] * inv1) << 16);
    u1.y = (unsigned)fb(o[1][et][2] * inv1) | ((unsigned)fb(o[1][et][3] * inv1) << 16);
    int ecol = wave * 128 + et * 16 + quad * 4;
    *(uint2*)(lds + (l15)*520 + ecol) = u0;
    *(uint2*)(lds + (16 + l15) * 520 + ecol) = u1;
  }
  __syncthreads();

  // ---- out-projection: D[m=cc][n=t] = w_out @ O^T, + bias + residual ----
  f32x4 oa[8][2];
#pragma unroll
  for (int i = 0; i < 8; ++i) {
    oa[i][0] = {0.f, 0.f, 0.f, 0.f};
    oa[i][1] = {0.f, 0.f, 0.f, 0.f};
  }
  for (int kc = 0; kc < 16; ++kc) {
    bf16x8 ob0 = frag_ld(lds + l15 * 520 + kc * 32 + quad * 8);
    bf16x8 ob1 = frag_ld(lds + (16 + l15) * 520 + kc * 32 + quad * 8);
#pragma unroll
    for (int es = 0; es < 8; ++es) {
      bf16x8 a = frag_ld(wbfo + (size_t)(wave * 128 + es * 16 + l15) * 512 + kc * 32 + quad * 8);
      oa[es][0] = MFMA(a, ob0, oa[es][0]);
      oa[es][1] = MFMA(a, ob1, oa[es][1]);
    }
  }
#pragma unroll
  for (int es = 0; es < 8; ++es) {
    int cc = wave * 128 + es * 16 + quad * 4;
    float b0 = ld(b_out, cc, f32), b1 = ld(b_out, cc + 1, f32);
    float b2 = ld(b_out, cc + 2, f32), b3 = ld(b_out, cc + 3, f32);
#pragma unroll
    for (int ts = 0; ts < 2; ++ts) {
      int t = t0 + ts * 16 + l15;
      float vr[4] = {oa[es][ts][0] + b0, oa[es][ts][1] + b1,
                     oa[es][ts][2] + b2, oa[es][ts][3] + b3};
#pragma unroll
      for (int r = 0; r < 4; ++r) {
        size_t oidx = ((size_t)(nn * C + cc + r) << 12) + t;
        float v = vr[r] + ld(x, oidx, f32);
        if (f32)
          ((float*)out)[oidx] = v;
        else
          ((unsigned short*)out)[oidx] = fb(v);
      }
    }
  }
}

// ---------------------------------------------------------------------------
extern "C" void kernel_launch(void* const* d_in, const int* in_sizes, int n_in,
                              void* d_out, int out_size, void* d_ws, size_t ws_size,
                              hipStream_t stream) {
  const void* x = d_in[0];
  const void* gn_scale = d_in[1];
  const void* gn_bias = d_in[2];
  const void* w_in = d_in[3];
  const void* b_in = d_in[4];
  const void* w_out = d_in[5];
  const void* b_out = d_in[6];
  (void)in_sizes; (void)n_in; (void)out_size;

  // ws: [stats 1KB | kv slots (8MB each) | wbf 2MB (w_in 1.5MB + w_out 0.5MB)]
  float* stats = (float*)d_ws;
  unsigned short* kv0 = (unsigned short*)((char*)d_ws + 1024);
  const size_t slotB = 8388608;
  const size_t need4 = 1024 + 4 * slotB + 2097152;

  gn_stats_kernel<<<NBATCH * GROUPS, 256, 0, stream>>>(x, w_in, stats);

  if (ws_size >= need4) {
    short* wbf = (short*)((char*)d_ws + 1024 + 4 * slotB);
    wconv_kernel<<<1024, 256, 0, stream>>>(w_in, w_out, wbf);
    kv_gemm_kernel<<<dim3(32, 4, 2), 256, 0, stream>>>(
        x, gn_scale, gn_bias, stats, w_in, b_in, wbf, kv0, 0);
    flash32_kernel<<<dim3(512), 256, 0, stream>>>(
        x, gn_scale, gn_bias, stats, w_in, b_in, wbf, wbf + 786432, kv0,
        b_out, d_out, 0, 1);
  } else {
    short* wbf = (short*)((char*)d_ws + 1024 + slotB);
    wconv_kernel<<<1024, 256, 0, stream>>>(w_in, w_out, wbf);
    for (int nn = 0; nn < NBATCH; ++nn) {
      kv_gemm_kernel<<<dim3(32, 1, 2), 256, 0, stream>>>(
          x, gn_scale, gn_bias, stats, w_in, b_in, wbf, kv0, nn);
      flash32_kernel<<<dim3(128), 256, 0, stream>>>(
          x, gn_scale, gn_bias, stats, w_in, b_in, wbf, wbf + 786432, kv0,
          b_out, d_out, nn, 0);
    }
  }
}

// Round 11
// 494.010 us; speedup vs baseline: 1.5260x; 1.5260x over previous
//
#include <hip/hip_runtime.h>
#include <hip/hip_bf16.h>

// n=4, c=512, h=w=64. Runtime dtype via detect_f32 (R3-proven).
#define NBATCH 4
#define C 512
#define HW 4096
#define GROUPS 32
#define EPSV 1e-5f
// attention scale folded with 1/ln2 (softmax in exp2 domain, R5-proven):
// 1/sqrt(512) * log2(e)
#define ATTN_SCALE_L2 0.0637587085f

typedef short bf16x8 __attribute__((ext_vector_type(8)));  // 8 bf16 = 4 VGPR
typedef float f32x4 __attribute__((ext_vector_type(4)));

__device__ __forceinline__ float bf(unsigned short u) {
  return __uint_as_float(((unsigned)u) << 16);
}
__device__ __forceinline__ unsigned short fb(float v) {
  __hip_bfloat16 h = __float2bfloat16(v);
  return *(unsigned short*)&h;
}
__device__ __forceinline__ bf16x8 frag_ld(const short* p) {
  return *(const bf16x8*)p;  // 16B-aligned by construction
}
#define MFMA(a, b, c) __builtin_amdgcn_mfma_f32_16x16x32_bf16((a), (b), (c), 0, 0, 0)

#define SCHED_FENCE() __builtin_amdgcn_sched_barrier(0)
// raw barrier (NO vmcnt drain) + compiler/scheduler fences (rule #18 / m152)
#define BAR()                                   \
  do {                                          \
    asm volatile("" ::: "memory");              \
    SCHED_FENCE();                              \
    __builtin_amdgcn_s_barrier();               \
    SCHED_FENCE();                              \
    asm volatile("" ::: "memory");              \
  } while (0)
#define WAITV(N)                                                  \
  do {                                                            \
    asm volatile("s_waitcnt vmcnt(" #N ")" ::: "memory");         \
    SCHED_FENCE();                                                \
  } while (0)
// drain DS queue before a raw barrier that PUBLISHES cross-wave LDS writes
// (raw s_barrier does not imply waitcnt; __syncthreads does).
#define WAITLGKM()                                                \
  do {                                                            \
    asm volatile("s_waitcnt lgkmcnt(0)" ::: "memory");            \
    SCHED_FENCE();                                                \
  } while (0)

// async global->LDS, 16B per lane; LDS dest is wave-uniform base + lane*16
__device__ __forceinline__ void gl_lds16(const short* g, short* l) {
  __builtin_amdgcn_global_load_lds(
      (const __attribute__((address_space(1))) unsigned int*)g,
      (__attribute__((address_space(3))) unsigned int*)l, 16, 0, 0);
}

__device__ __forceinline__ void unpack8(uint4 w, float* f) {
  f[0] = __uint_as_float(w.x << 16);
  f[1] = __uint_as_float(w.x & 0xFFFF0000u);
  f[2] = __uint_as_float(w.y << 16);
  f[3] = __uint_as_float(w.y & 0xFFFF0000u);
  f[4] = __uint_as_float(w.z << 16);
  f[5] = __uint_as_float(w.z & 0xFFFF0000u);
  f[6] = __uint_as_float(w.w << 16);
  f[7] = __uint_as_float(w.w & 0xFFFF0000u);
}

// Runtime dtype detection (R3-proven).
__device__ __forceinline__ bool detect_f32(const void* w_in) {
  const unsigned short* u = (const unsigned short*)w_in;
  bool f32 = false;
#pragma unroll
  for (int i = 0; i < 64; ++i) {
    float v = bf(u[i]);
    if (!(fabsf(v) < 1e3f)) f32 = true;  // NaN -> true
  }
  return f32;
}
__device__ __forceinline__ float ld(const void* p, size_t i, bool f32) {
  if (f32) return ((const float*)p)[i];
  return bf(((const unsigned short*)p)[i]);
}

// Stage GN-normalized x rows [t0, t0+32) into xn[32][520] (bf16). R3-proven.
__device__ __forceinline__ void stage_xn(short* xn, const void* x,
                                         const void* gsc, const void* gbi,
                                         const float* stats, int nn, int t0,
                                         bool f32) {
  const int tid = threadIdx.x;
  const int part = tid & 3, crel = tid >> 2;
  for (int c0 = 0; c0 < 512; c0 += 64) {
    int c = c0 + crel;
    float rr = stats[128 + nn * GROUPS + (c >> 4)];
    float mu = stats[nn * GROUPS + (c >> 4)];
    float scl = ld(gsc, c, f32) * rr;
    float sft = ld(gbi, c, f32) - mu * scl;
    float f[8];
    if (f32) {
      const float4* p = (const float4*)((const float*)x +
                                        ((size_t)(nn * C + c) << 12) + t0 + part * 8);
      float4 r0 = p[0], r1 = p[1];
      f[0] = r0.x; f[1] = r0.y; f[2] = r0.z; f[3] = r0.w;
      f[4] = r1.x; f[5] = r1.y; f[6] = r1.z; f[7] = r1.w;
    } else {
      uint4 raw = *(const uint4*)((const unsigned short*)x +
                                  ((size_t)(nn * C + c) << 12) + t0 + part * 8);
      unpack8(raw, f);
    }
#pragma unroll
    for (int j = 0; j < 8; ++j)
      xn[(part * 8 + j) * 520 + c] = (short)fb(f[j] * scl + sft);
  }
}

// ---------------------------------------------------------------------------
// gn_part — VECTORIZED GroupNorm partial sums (G13: scalar bf16/f32 loads
// were the defect; 128-block grid left half the GPU idle). Grid 256:
// block b covers group g=b>>1, half h=b&1 (32768 elems), float4/uint4 loads.
// Partials -> gpart[b], gpart[256+b].
// ---------------------------------------------------------------------------
__global__ __launch_bounds__(256) void gn_part_kernel(
    const void* __restrict__ x, const void* __restrict__ w_in,
    float* __restrict__ gpart) {
  const bool f32 = detect_f32(w_in);
  const int b = blockIdx.x;
  const size_t base = ((size_t)(b >> 1) << 16) + ((size_t)(b & 1) << 15);
  float s = 0.f, ss = 0.f;
  if (f32) {
    const float4* p = (const float4*)((const float*)x + base);
    for (int i = threadIdx.x; i < 8192; i += 256) {
      float4 v = p[i];
      s += (v.x + v.y) + (v.z + v.w);
      ss += (v.x * v.x + v.y * v.y) + (v.z * v.z + v.w * v.w);
    }
  } else {
    const uint4* p = (const uint4*)((const unsigned short*)x + base);
    for (int i = threadIdx.x; i < 4096; i += 256) {
      float f[8];
      unpack8(p[i], f);
#pragma unroll
      for (int j = 0; j < 8; ++j) {
        s += f[j];
        ss += f[j] * f[j];
      }
    }
  }
  __shared__ float rs[256], rq[256];
  rs[threadIdx.x] = s;
  rq[threadIdx.x] = ss;
  __syncthreads();
  for (int off = 128; off > 0; off >>= 1) {
    if (threadIdx.x < off) {
      rs[threadIdx.x] += rs[threadIdx.x + off];
      rq[threadIdx.x] += rq[threadIdx.x + off];
    }
    __syncthreads();
  }
  if (threadIdx.x == 0) {
    gpart[b] = rs[0];
    gpart[256 + b] = rq[0];
  }
}

// finalize: combine the 2 halves per group (fixed order -> deterministic).
__global__ __launch_bounds__(128) void gn_final_kernel(
    const float* __restrict__ gpart, float* __restrict__ stats) {
  int g = threadIdx.x;  // 128 groups
  float s = gpart[2 * g] + gpart[2 * g + 1];
  float ss = gpart[256 + 2 * g] + gpart[256 + 2 * g + 1];
  float m = s * (1.0f / 65536.0f);
  float var = ss * (1.0f / 65536.0f) - m * m;
  stats[g] = m;
  stats[128 + g] = rsqrtf(var + EPSV);
}

// ---------------------------------------------------------------------------
// wconv — one-time weight conversion to bf16 (R8-proven verbatim).
// ---------------------------------------------------------------------------
__global__ __launch_bounds__(256) void wconv_kernel(
    const void* __restrict__ w_in, const void* __restrict__ w_out,
    short* __restrict__ wbf) {
  const bool f32 = detect_f32(w_in);
  size_t i = ((size_t)blockIdx.x * 256 + threadIdx.x) * 4;
  const void* src;
  size_t off;
  if (i < 786432) {
    src = w_in;
    off = i;
  } else {
    src = w_out;
    off = i - 786432;
  }
  if (f32) {
    float4 v = *(const float4*)((const float*)src + off);
    uint2 u;
    u.x = (unsigned)fb(v.x) | ((unsigned)fb(v.y) << 16);
    u.y = (unsigned)fb(v.z) | ((unsigned)fb(v.w) << 16);
    *(uint2*)(wbf + i) = u;
  } else {
    *(uint2*)(wbf + i) = *(const uint2*)((const unsigned short*)src + off);
  }
}

// ---------------------------------------------------------------------------
// kv_gemm — R9-PROVEN VERBATIM (R10's weight-reuse tiling regressed 2x:
// blocks/CU 2->1 + serial tsub loop; parallelism beats traffic). ONE block
// per (t0, nn): stage_xn once, waves 0,1 = K / 2,3 = V (acc[16][2]),
// swizzled tile images assembled in LDS, linear coalesced copy-out.
// ---------------------------------------------------------------------------
__global__ __launch_bounds__(256, 2) void kv_gemm_kernel(
    const void* __restrict__ x, const void* __restrict__ gsc,
    const void* __restrict__ gbi, const float* __restrict__ stats,
    const void* __restrict__ w_in, const void* __restrict__ b_in,
    const short* __restrict__ wbf, unsigned short* __restrict__ kvbase,
    int nn0) {
  const bool f32 = detect_f32(w_in);
  const int nn = nn0 + blockIdx.y;
  unsigned short* kbuf = kvbase + (size_t)blockIdx.y * 4194304;
  unsigned short* vbuf = kbuf + 2097152;
  __shared__ __align__(16) short xn[32 * 520];  // 16640 >= 16384 stage reuse
  const int tid = threadIdx.x;
  const int wave = tid >> 6, lane = tid & 63, l15 = lane & 15, quad = lane >> 4;
  const int t0 = blockIdx.x * 32;

  stage_xn(xn, x, gsc, gbi, stats, nn, t0, f32);
  __syncthreads();

  const int wbase = 512 + wave * 256;  // w_in row base (K: w0,w1; V: w2,w3)

  f32x4 acc[16][2];
#pragma unroll
  for (int i = 0; i < 16; ++i) {
    acc[i][0] = {0.f, 0.f, 0.f, 0.f};
    acc[i][1] = {0.f, 0.f, 0.f, 0.f};
  }

  for (int kc = 0; kc < 16; ++kc) {
    bf16x8 b0f = frag_ld(xn + l15 * 520 + kc * 32 + quad * 8);
    bf16x8 b1f = frag_ld(xn + (16 + l15) * 520 + kc * 32 + quad * 8);
#pragma unroll
    for (int es = 0; es < 16; ++es) {
      bf16x8 a = frag_ld(wbf + (size_t)(wbase + es * 16 + l15) * 512 + kc * 32 + quad * 8);
      acc[es][0] = MFMA(a, b0f, acc[es][0]);
      acc[es][1] = MFMA(a, b1f, acc[es][1]);
    }
  }
  __syncthreads();  // xn b-frag reads done; reuse xn[0:16384) as tile stage

  // ---- K tile: waves 0,1 write swizzled image into LDS ----
  if (wave < 2) {
#pragma unroll
    for (int es = 0; es < 16; ++es) {
      int bidx = wbase + es * 16 + quad * 4;
      float b0 = ld(b_in, bidx, f32), b1 = ld(b_in, bidx + 1, f32);
      float b2 = ld(b_in, bidx + 2, f32), b3 = ld(b_in, bidx + 3, f32);
      int ecol = wave * 256 + es * 16 + quad * 4;
#pragma unroll
      for (int ts = 0; ts < 2; ++ts) {
        int trel = ts * 16 + l15;
        int sw = (((ecol >> 3) ^ (trel & 7)) << 3) | (ecol & 7);
        uint2 u;
        u.x = (unsigned)fb(acc[es][ts][0] + b0) |
              ((unsigned)fb(acc[es][ts][1] + b1) << 16);
        u.y = (unsigned)fb(acc[es][ts][2] + b2) |
              ((unsigned)fb(acc[es][ts][3] + b3) << 16);
        *(uint2*)(xn + trel * 512 + sw) = u;
      }
    }
  }
  __syncthreads();
  {  // linear coalesced copy-out: 32KB, 16B/lane
    short* dst = (short*)kbuf + (size_t)t0 * 512;
#pragma unroll
    for (int j = 0; j < 8; ++j) {
      int idx = (j * 256 + tid) * 8;
      *(uint4*)(dst + idx) = *(const uint4*)(xn + idx);
    }
  }
  __syncthreads();

  // ---- V tile: waves 2,3 write swizzled image into LDS ----
  if (wave >= 2) {
#pragma unroll
    for (int es = 0; es < 16; ++es) {
      int bidx = wbase + es * 16 + quad * 4;
      float bb[4] = {ld(b_in, bidx, f32), ld(b_in, bidx + 1, f32),
                     ld(b_in, bidx + 2, f32), ld(b_in, bidx + 3, f32)};
      int ecol = (wave - 2) * 256 + es * 16 + quad * 4;
#pragma unroll
      for (int ts = 0; ts < 2; ++ts) {
        int trel = ts * 16 + l15;
#pragma unroll
        for (int i = 0; i < 4; ++i) {
          int e = ecol + i;
          xn[e * 32 + ((((trel >> 3) ^ ((e >> 1) & 3)) << 3)) + (trel & 7)] =
              fb(acc[es][ts][i] + bb[i]);
        }
      }
    }
  }
  __syncthreads();
  {  // linear coalesced copy-out: 32KB, 16B/lane
    short* dst = (short*)vbuf + (size_t)(t0 >> 5) * 16384;
#pragma unroll
    for (int j = 0; j < 8; ++j) {
      int idx = (j * 256 + tid) * 8;
      *(uint4*)(dst + idx) = *(const uint4*)(xn + idx);
    }
  }
}

// ---------------------------------------------------------------------------
// flash32 — R8-proven VERBATIM (348-353 µs, three passing rounds): quadrant
// split, parallel hmf publish, split S chains, pre-converted weights.
// ---------------------------------------------------------------------------
__global__ __launch_bounds__(256, 2) void flash32_kernel(
    const void* __restrict__ x, const void* __restrict__ gsc,
    const void* __restrict__ gbi, const float* __restrict__ stats,
    const void* __restrict__ w_in, const void* __restrict__ b_in,
    const short* __restrict__ wbf, const short* __restrict__ wbfo,
    const unsigned short* __restrict__ kvbase,
    const void* __restrict__ b_out, void* __restrict__ out, int nn0,
    int conc) {
  const bool f32 = detect_f32(w_in);
  int nn, t0, slot;
  if (conc) {
    int xcd = blockIdx.x & 7;
    nn = xcd >> 1;
    slot = nn;
    t0 = ((((xcd & 1) << 6) | (blockIdx.x >> 3))) << 5;
  } else {
    nn = nn0; slot = 0; t0 = blockIdx.x << 5;
  }
  const unsigned short* kbuf = kvbase + (size_t)slot * 4194304;
  const unsigned short* vbuf = kbuf + 2097152;

  // LDS: RA 16640 | RB 16640 | Ps 1280 | hmf 256f | lbf 64f = 70,400 B
  __shared__ __align__(16) short lds[35200];
  short* RA = lds;                 // xn (Q phase) -> Ktile -> O park
  short* RB = lds + 16640;         // Qs (Q phase) -> Vtile
  short* Ps = lds + 33280;         // block-shared P [32 qrow][40 t']
  float* hmf = (float*)(lds + 34560);  // [2 th][32 qrow][4 quad] partial max
  float* lbf = (float*)(lds + 35072);  // [2 th][32 qrow] final l halves
  const int tid = threadIdx.x;
  const int wave = tid >> 6, lane = tid & 63, l15 = lane & 15, quad = lane >> 4;
  const int th = wave & 1;   // t' half: rows th*16..+16 of K tile
  const int qh = wave >> 1;  // q half: S quadrant rows qh*16..+16

  // ================= Q phase (R5-proven; weights from wbf) ================
  bf16x8 q[16];  // wave's 16 q-rows x 512 c, B-frag layout (n=qrow, k=c)
  stage_xn(RA, x, gsc, gbi, stats, nn, t0, f32);
  __syncthreads();
  {
    f32x4 qacc[8][2];
#pragma unroll
    for (int i = 0; i < 8; ++i) {
      qacc[i][0] = {0.f, 0.f, 0.f, 0.f};
      qacc[i][1] = {0.f, 0.f, 0.f, 0.f};
    }
    for (int kc = 0; kc < 16; ++kc) {
      bf16x8 bx0 = frag_ld(RA + l15 * 520 + kc * 32 + quad * 8);
      bf16x8 bx1 = frag_ld(RA + (16 + l15) * 520 + kc * 32 + quad * 8);
#pragma unroll
      for (int es = 0; es < 8; ++es) {
        bf16x8 a = frag_ld(wbf + (size_t)(wave * 128 + es * 16 + l15) * 512 + kc * 32 + quad * 8);
        qacc[es][0] = MFMA(a, bx0, qacc[es][0]);
        qacc[es][1] = MFMA(a, bx1, qacc[es][1]);
      }
    }
    // D[m=e][n=t] -> Qs[t][e] = (acc + b_in[e]) * ATTN_SCALE_L2 (bf16)
#pragma unroll
    for (int es = 0; es < 8; ++es) {
      int e0 = wave * 128 + es * 16 + quad * 4;
      float b0 = ld(b_in, e0, f32), b1 = ld(b_in, e0 + 1, f32);
      float b2 = ld(b_in, e0 + 2, f32), b3 = ld(b_in, e0 + 3, f32);
#pragma unroll
      for (int ts = 0; ts < 2; ++ts) {
        int t = ts * 16 + l15;
        uint2 u;
        u.x = (unsigned)fb((qacc[es][ts][0] + b0) * ATTN_SCALE_L2) |
              ((unsigned)fb((qacc[es][ts][1] + b1) * ATTN_SCALE_L2) << 16);
        u.y = (unsigned)fb((qacc[es][ts][2] + b2) * ATTN_SCALE_L2) |
              ((unsigned)fb((qacc[es][ts][3] + b3) * ATTN_SCALE_L2) << 16);
        *(uint2*)(RB + t * 520 + e0) = u;
      }
    }
    __syncthreads();
#pragma unroll
    for (int kc = 0; kc < 16; ++kc)
      q[kc] = frag_ld(RB + (qh * 16 + l15) * 520 + kc * 32 + quad * 8);
    __syncthreads();
  }

// ================= K/V tile staging macros (R5-proven) =================
#define STAGE_K(tk)                                                           \
  {                                                                           \
    const short* s_ = (const short*)kbuf + (size_t)(tk)*16384 + wave * 4096 + \
                      lane * 8;                                               \
    short* d_ = RA + wave * 4096;                                             \
    _Pragma("unroll") for (int i_ = 0; i_ < 8; ++i_)                          \
        gl_lds16(s_ + i_ * 512, d_ + i_ * 512);                               \
  }
#define STAGE_V(tk)                                                           \
  {                                                                           \
    const short* s_ = (const short*)vbuf + (size_t)(tk)*16384 + wave * 4096 + \
                      lane * 8;                                               \
    short* d_ = RB + wave * 4096;                                             \
    _Pragma("unroll") for (int i_ = 0; i_ < 8; ++i_)                          \
        gl_lds16(s_ + i_ * 512, d_ + i_ * 512);                               \
  }

  f32x4 o[2][8];  // O[qh half][e-tile et]: e = wave*128 + et*16 + quad*4+r
#pragma unroll
  for (int hh = 0; hh < 2; ++hh)
#pragma unroll
    for (int et = 0; et < 8; ++et) o[hh][et] = {0.f, 0.f, 0.f, 0.f};
  float mrow2[2] = {-3.0e38f, -3.0e38f};  // running max per q-half (lane=qrow)
  float lpart = 0.f;                      // own-quadrant partial sum

  STAGE_K(0);
  STAGE_V(0);

  for (int tk = 0; tk < 128; ++tk) {
    WAITV(8);  // K(tk) landed (V(tk) may still fly)
    BAR();

    // ---- S quadrant = K[th half] @ Q[qh half]^T: 2 independent chains ----
    f32x4 sA = {0.f, 0.f, 0.f, 0.f}, sB = {0.f, 0.f, 0.f, 0.f};
    __builtin_amdgcn_s_setprio(1);
#pragma unroll
    for (int kc = 0; kc < 16; kc += 2) {
      int g0 = ((kc * 4 + quad) ^ (l15 & 7)) * 8;        // inverse kbuf swz
      int g1 = (((kc + 1) * 4 + quad) ^ (l15 & 7)) * 8;
      bf16x8 kb0 = frag_ld(RA + (th * 16 + l15) * 512 + g0);
      bf16x8 kb1 = frag_ld(RA + (th * 16 + l15) * 512 + g1);
      sA = MFMA(kb0, q[kc], sA);
      sB = MFMA(kb1, q[kc + 1], sB);
    }
    __builtin_amdgcn_s_setprio(0);
    f32x4 s = sA + sB;
    // publish per-quad partial max IMMEDIATELY (no shfl chain)
    float hm = fmaxf(fmaxf(s[0], s[1]), fmaxf(s[2], s[3]));
    hmf[th * 128 + (qh * 16 + l15) * 4 + quad] = hm;
    WAITLGKM();  // publish hmf before raw barrier
    BAR();       // K reads done (stage next) + hmf visible
    if (tk < 127) STAGE_K(tk + 1);  // flies under softmax + PV

    // ---- combined tile max from 4 PARALLEL b128 reads + fmax tree ----
    float4 a0 = *(const float4*)&hmf[l15 * 4];                 // th0, qh0 rows
    float4 a1 = *(const float4*)&hmf[128 + l15 * 4];           // th1, qh0 rows
    float4 c0 = *(const float4*)&hmf[(16 + l15) * 4];          // th0, qh1 rows
    float4 c1 = *(const float4*)&hmf[128 + (16 + l15) * 4];    // th1, qh1 rows
    float m0 = fmaxf(fmaxf(fmaxf(a0.x, a0.y), fmaxf(a0.z, a0.w)),
                     fmaxf(fmaxf(a1.x, a1.y), fmaxf(a1.z, a1.w)));
    float m1 = fmaxf(fmaxf(fmaxf(c0.x, c0.y), fmaxf(c0.z, c0.w)),
                     fmaxf(fmaxf(c1.x, c1.y), fmaxf(c1.z, c1.w)));
    bool grow = (m0 > mrow2[0]) | (m1 > mrow2[1]);
    if (__any(grow)) {  // identical verdict in all waves (shared inputs)
      float n0 = fmaxf(mrow2[0], m0), n1 = fmaxf(mrow2[1], m1);
      float sc0 = exp2f(mrow2[0] - n0), sc1 = exp2f(mrow2[1] - n1);
      mrow2[0] = n0;
      mrow2[1] = n1;
      lpart *= (qh ? sc1 : sc0);
#pragma unroll
      for (int et = 0; et < 8; ++et) {
        o[0][et] *= sc0;
        o[1][et] *= sc1;
      }
    }
    float mq = qh ? mrow2[1] : mrow2[0];
    float p0 = exp2f(s[0] - mq), p1 = exp2f(s[1] - mq);
    float p2 = exp2f(s[2] - mq), p3 = exp2f(s[3] - mq);
    lpart += (p0 + p1) + (p2 + p3);
    uint2 u;
    u.x = (unsigned)fb(p0) | ((unsigned)fb(p1) << 16);
    u.y = (unsigned)fb(p2) | ((unsigned)fb(p3) << 16);
    *(uint2*)(Ps + (qh * 16 + l15) * 40 + th * 16 + quad * 4) = u;
    WAITLGKM();  // publish Ps before raw barrier
    if (tk == 127) { WAITV(0); } else { WAITV(8); }  // V(tk) landed
    BAR();

    // ---- PV: O[e quarter][all 32 q] += V^T @ P; V-frag reused 2x ----
    bf16x8 pa0 = frag_ld(Ps + l15 * 40 + quad * 8);         // qh=0 rows
    bf16x8 pa1 = frag_ld(Ps + (16 + l15) * 40 + quad * 8);  // qh=1 rows
    __builtin_amdgcn_s_setprio(1);
#pragma unroll
    for (int et = 0; et < 8; ++et) {
      int e = wave * 128 + et * 16 + l15;
      bf16x8 vb = frag_ld(RB + e * 32 + ((quad ^ ((l15 >> 1) & 3)) << 3));
      o[0][et] = MFMA(vb, pa0, o[0][et]);
      o[1][et] = MFMA(vb, pa1, o[1][et]);
    }
    __builtin_amdgcn_s_setprio(0);
    BAR();  // V + Ps reads done
    if (tk < 127) STAGE_V(tk + 1);  // flies under next S
  }

  // ---- final l: in-wave quad reduce, cross-wave th combine ----
  lpart += __shfl_xor(lpart, 16);
  lpart += __shfl_xor(lpart, 32);
  if (quad == 0) lbf[th * 32 + qh * 16 + l15] = lpart;
  __syncthreads();
  float inv0 = 1.0f / (lbf[l15] + lbf[32 + l15]);
  float inv1 = 1.0f / (lbf[16 + l15] + lbf[48 + l15]);

  // ---- park O (bf16) in Opark[32][520] over lds base ----
#pragma unroll
  for (int et = 0; et < 8; ++et) {
    uint2 u0, u1;
    u0.x = (unsigned)fb(o[0][et][0] * inv0) | ((unsigned)fb(o[0][et][1] * inv0) << 16);
    u0.y = (unsigned)fb(o[0][et][2] * inv0) | ((unsigned)fb(o[0][et][3] * inv0) << 16);
    u1.x = (unsigned)fb(o[1][et][0] * inv1) | ((unsigned)fb(o[1][et][1] * inv1) << 16);
    u1.y = (unsigned)fb(o[1][et][2] * inv1) | ((unsigned)fb(o[1][et][3] * inv1) << 16);
    int ecol = wave * 128 + et * 16 + quad * 4;
    *(uint2*)(lds + (l15)*520 + ecol) = u0;
    *(uint2*)(lds + (16 + l15) * 520 + ecol) = u1;
  }
  __syncthreads();

  // ---- out-projection: D[m=cc][n=t] = w_out @ O^T, + bias + residual ----
  f32x4 oa[8][2];
#pragma unroll
  for (int i = 0; i < 8; ++i) {
    oa[i][0] = {0.f, 0.f, 0.f, 0.f};
    oa[i][1] = {0.f, 0.f, 0.f, 0.f};
  }
  for (int kc = 0; kc < 16; ++kc) {
    bf16x8 ob0 = frag_ld(lds + l15 * 520 + kc * 32 + quad * 8);
    bf16x8 ob1 = frag_ld(lds + (16 + l15) * 520 + kc * 32 + quad * 8);
#pragma unroll
    for (int es = 0; es < 8; ++es) {
      bf16x8 a = frag_ld(wbfo + (size_t)(wave * 128 + es * 16 + l15) * 512 + kc * 32 + quad * 8);
      oa[es][0] = MFMA(a, ob0, oa[es][0]);
      oa[es][1] = MFMA(a, ob1, oa[es][1]);
    }
  }
#pragma unroll
  for (int es = 0; es < 8; ++es) {
    int cc = wave * 128 + es * 16 + quad * 4;
    float b0 = ld(b_out, cc, f32), b1 = ld(b_out, cc + 1, f32);
    float b2 = ld(b_out, cc + 2, f32), b3 = ld(b_out, cc + 3, f32);
#pragma unroll
    for (int ts = 0; ts < 2; ++ts) {
      int t = t0 + ts * 16 + l15;
      float vr[4] = {oa[es][ts][0] + b0, oa[es][ts][1] + b1,
                     oa[es][ts][2] + b2, oa[es][ts][3] + b3};
#pragma unroll
      for (int r = 0; r < 4; ++r) {
        size_t oidx = ((size_t)(nn * C + cc + r) << 12) + t;
        float v = vr[r] + ld(x, oidx, f32);
        if (f32)
          ((float*)out)[oidx] = v;
        else
          ((unsigned short*)out)[oidx] = fb(v);
      }
    }
  }
}

// ---------------------------------------------------------------------------
extern "C" void kernel_launch(void* const* d_in, const int* in_sizes, int n_in,
                              void* d_out, int out_size, void* d_ws, size_t ws_size,
                              hipStream_t stream) {
  const void* x = d_in[0];
  const void* gn_scale = d_in[1];
  const void* gn_bias = d_in[2];
  const void* w_in = d_in[3];
  const void* b_in = d_in[4];
  const void* w_out = d_in[5];
  const void* b_out = d_in[6];
  (void)in_sizes; (void)n_in; (void)out_size;

  // ws: [stats 1KB | kv slots (8MB each) | wbf 2MB | gpart 2KB]
  float* stats = (float*)d_ws;
  unsigned short* kv0 = (unsigned short*)((char*)d_ws + 1024);
  const size_t slotB = 8388608;
  const size_t need4 = 1024 + 4 * slotB + 2097152 + 2048;

  if (ws_size >= need4) {
    short* wbf = (short*)((char*)d_ws + 1024 + 4 * slotB);
    float* gpart = (float*)((char*)d_ws + 1024 + 4 * slotB + 2097152);
    gn_part_kernel<<<256, 256, 0, stream>>>(x, w_in, gpart);
    gn_final_kernel<<<1, 128, 0, stream>>>(gpart, stats);
    wconv_kernel<<<1024, 256, 0, stream>>>(w_in, w_out, wbf);
    kv_gemm_kernel<<<dim3(128, 4), 256, 0, stream>>>(
        x, gn_scale, gn_bias, stats, w_in, b_in, wbf, kv0, 0);
    flash32_kernel<<<dim3(512), 256, 0, stream>>>(
        x, gn_scale, gn_bias, stats, w_in, b_in, wbf, wbf + 786432, kv0,
        b_out, d_out, 0, 1);
  } else {
    short* wbf = (short*)((char*)d_ws + 1024 + slotB);
    float* gpart = (float*)((char*)d_ws + 1024 + slotB + 2097152);
    gn_part_kernel<<<256, 256, 0, stream>>>(x, w_in, gpart);
    gn_final_kernel<<<1, 128, 0, stream>>>(gpart, stats);
    wconv_kernel<<<1024, 256, 0, stream>>>(w_in, w_out, wbf);
    for (int nn = 0; nn < NBATCH; ++nn) {
      kv_gemm_kernel<<<dim3(128, 1), 256, 0, stream>>>(
          x, gn_scale, gn_bias, stats, w_in, b_in, wbf, kv0, nn);
      flash32_kernel<<<dim3(128), 256, 0, stream>>>(
          x, gn_scale, gn_bias, stats, w_in, b_in, wbf, wbf + 786432, kv0,
          b_out, d_out, nn, 0);
    }
  }
}